// Round 1
// 1265.569 us; speedup vs baseline: 1.2129x; 1.2129x over previous
//
#include <hip/hip_runtime.h>
#include <hip/hip_bf16.h>
#include <stddef.h>

typedef unsigned short ushort_t;
typedef __bf16 bf16x8 __attribute__((ext_vector_type(8)));
typedef float  f32x4  __attribute__((ext_vector_type(4)));

#define GAS __attribute__((address_space(1)))
#define LAS __attribute__((address_space(3)))

__device__ __forceinline__ ushort_t f2bf(float f) {
    union { float f; unsigned u; } v; v.f = f;
    unsigned r = v.u + 0x7fffu + ((v.u >> 16) & 1u);   // RNE
    return (ushort_t)(r >> 16);
}

// gelu(x) = x * sigmoid(2u), u = 0.79788456*(x + 0.044715 x^3)
__device__ __forceinline__ float gelu_tanh(float x) {
    float u = 0.7978845608028654f * x * (1.0f + 0.044715f * x * x);
    float e = __builtin_amdgcn_exp2f(-2.8853900817779268f * u);   // exp(-2u)
    return x * __builtin_amdgcn_rcpf(1.0f + e);
}

__device__ __forceinline__ void gload_lds16(const ushort_t* g, ushort_t* l) {
    __builtin_amdgcn_global_load_lds((const GAS void*)g, (LAS void*)l, 16, 0, 0);
}

// ---------------- phase A: x fp32 -> bf16, fused mean-pool partials ----------------
__global__ __launch_bounds__(256) void k_convert_x_pool(const float* __restrict__ x,
                                                        ushort_t* __restrict__ Xbf,
                                                        float* __restrict__ part) {
    int b = blockIdx.x, c = blockIdx.y, t = threadIdx.x;
    int d = t * 4;
    const float* xp = x + ((size_t)b * 1024 + (size_t)c * 64) * 1024;
    ushort_t* op = Xbf + ((size_t)b * 1024 + (size_t)c * 64) * 1024;
    float s0 = 0, s1 = 0, s2 = 0, s3 = 0;
    for (int n = 0; n < 64; ++n) {
        float4 v = *(const float4*)(xp + (size_t)n * 1024 + d);
        s0 += v.x; s1 += v.y; s2 += v.z; s3 += v.w;
        ushort4 o; o.x = f2bf(v.x); o.y = f2bf(v.y); o.z = f2bf(v.z); o.w = f2bf(v.w);
        *(ushort4*)(op + (size_t)n * 1024 + d) = o;
    }
    float4 s; s.x = s0; s.y = s1; s.z = s2; s.w = s3;
    *(float4*)(part + ((size_t)b * 16 + c) * 1024 + d) = s;
}

// ---------------- router ----------------
__global__ __launch_bounds__(256) void k_router(const float* __restrict__ part,
                                                const float* __restrict__ w_gate,
                                                const float* __restrict__ b_gate,
                                                const float* __restrict__ alpha,
                                                int* __restrict__ eidx,
                                                float* __restrict__ gsw) {
    __shared__ float red[8 * 256];
    int b = blockIdx.x, t = threadIdx.x;
    float le[8];
#pragma unroll
    for (int e = 0; e < 8; ++e) le[e] = 0.f;
    for (int i = 0; i < 4; ++i) {
        int d = t + i * 256;
        float s = 0.f;
#pragma unroll
        for (int c = 0; c < 16; ++c) s += part[((size_t)b * 16 + c) * 1024 + d];
        s *= (1.0f / 1024.0f);
#pragma unroll
        for (int e = 0; e < 8; ++e) le[e] += s * w_gate[(size_t)d * 8 + e];
    }
#pragma unroll
    for (int e = 0; e < 8; ++e) red[e * 256 + t] = le[e];
    __syncthreads();
    for (int s2 = 128; s2 > 0; s2 >>= 1) {
        if (t < s2)
#pragma unroll
            for (int e = 0; e < 8; ++e) red[e * 256 + t] += red[e * 256 + t + s2];
        __syncthreads();
    }
    if (t == 0) {
        float lg[8];
#pragma unroll
        for (int e = 0; e < 8; ++e) lg[e] = red[e * 256] + b_gate[e];
        float mx = lg[0];
#pragma unroll
        for (int e = 1; e < 8; ++e) mx = fmaxf(mx, lg[e]);
        float pe[8];
#pragma unroll
        for (int e = 0; e < 8; ++e) pe[e] = expf(lg[e] - mx);
        int i0 = 0;
        for (int e = 1; e < 8; ++e) if (pe[e] > pe[i0]) i0 = e;
        int i1 = -1;
        for (int e = 0; e < 8; ++e) { if (e == i0) continue; if (i1 < 0 || pe[e] > pe[i1]) i1 = e; }
        float a = fminf(fmaxf(alpha[0], 0.1f), 1.0f);
        float inv = (1.0f - a) / (pe[i0] + pe[i1]);
        eidx[2 * b] = i0; eidx[2 * b + 1] = i1;
        gsw[2 * b] = pe[i0] * inv; gsw[2 * b + 1] = pe[i1] * inv;
    }
}

// ---------------- transpose+convert: fp32 [Z][R][C] -> bf16 [Z][C][R] ----------------
__global__ __launch_bounds__(256) void k_transpose_cvt(const float* __restrict__ src,
                                                       ushort_t* __restrict__ dst,
                                                       int R, int C) {
    __shared__ float tile[64][65];
    int z = blockIdx.z;
    const float* s = src + (size_t)z * R * C;
    ushort_t* d = dst + (size_t)z * R * C;
    int c0 = blockIdx.x * 64, r0 = blockIdx.y * 64;
    int t = threadIdx.x;
    int tc = (t & 15) * 4, tr = t >> 4;
#pragma unroll
    for (int i = 0; i < 4; ++i) {
        int r = tr + i * 16;
        float4 v = *(const float4*)(s + (size_t)(r0 + r) * C + c0 + tc);
        tile[r][tc] = v.x; tile[r][tc + 1] = v.y; tile[r][tc + 2] = v.z; tile[r][tc + 3] = v.w;
    }
    __syncthreads();
    int wc = t >> 2, wr = (t & 3) * 16;
#pragma unroll
    for (int i = 0; i < 4; ++i) {
        ushort4 o;
        o.x = f2bf(tile[wr + i * 4 + 0][wc]);
        o.y = f2bf(tile[wr + i * 4 + 1][wc]);
        o.z = f2bf(tile[wr + i * 4 + 2][wc]);
        o.w = f2bf(tile[wr + i * 4 + 3][wc]);
        *(ushort4*)(d + (size_t)(c0 + wc) * R + r0 + wr + i * 4) = o;
    }
}

// ---------------- epilogues ----------------
struct EpiGeluStore {
    ushort_t* H; int ldh; const float* bias; float scale;
    __device__ void operator()(int r, int c, f32x4 v) const {
        float bc = bias[c];
#pragma unroll
        for (int i = 0; i < 4; ++i)
            H[(size_t)(r + i) * ldh + c] = f2bf(scale * gelu_tanh(v[i] + bc));
    }
};
struct EpiMainOut {
    float* out; const float* bias; float a;
    __device__ void operator()(int r, int c, f32x4 v) const {
        float bc = bias[c];
#pragma unroll
        for (int i = 0; i < 4; ++i) out[(size_t)(r + i) * 1024 + c] = a * (v[i] + bc);
    }
};
struct EpiExpertOut {
    float* out; const float* b0; const float* b1; float g0, g1;
    __device__ void operator()(int r, int c, f32x4 v) const {
        float bc = g0 * b0[c] + g1 * b1[c];
#pragma unroll
        for (int i = 0; i < 4; ++i) out[(size_t)(r + i) * 1024 + c] += v[i] + bc;
    }
};

// ---------------- GEMM core: C 256x256 += A[M][K] * Bt[N][K]^T ----------------
// T3+T4+T5 stack: 512 threads (8 waves, 2M x 4N wave grid), BK=32, 3-stage LDS
// pipeline (3 x 32 KB buffers), counted vmcnt (never 0 in the main loop), raw
// s_barrier phases, setprio(1) around each 16-MFMA cluster.
//
// Pipeline invariant (provably race-free):
//   group t computes buf[t%3] and issues the 4 global_load_lds for K-tile t+2
//   into buf[(t+2)%3] (last read in group t-1, all waves past that barrier).
//   Group-end s_waitcnt vmcnt(4) guarantees K-tile t+1 landed while leaving
//   t+2's 4 loads in flight across the barrier.
//
// LDS read swizzle: granule kg ^= (row>>1)&3 (4 granules of 16B per 64B row)
// -> 2 lanes/bank on ds_read_b128 (free). global_load_lds writes linearly; the
// swizzle is applied by pre-swizzling the per-lane GLOBAL source granule.
template <int NSEG, typename Epi>
__device__ __forceinline__ void gemm256(const ushort_t* __restrict__ A0,
                                        const ushort_t* __restrict__ A1,
                                        const ushort_t* __restrict__ B0,
                                        const ushort_t* __restrict__ B1,
                                        int segK, int m0, int n0, Epi epi) {
    __shared__ ushort_t lds[3 * 16384];      // 3 bufs x (A 8192 + B 8192 elems) = 96 KB
    const int tid  = threadIdx.x;
    const int lane = tid & 63;
    const int w    = tid >> 6;               // wave 0..7
    const int wm   = w >> 2, wn = w & 3;     // 2 x 4 wave grid -> 128x64 per wave
    const int l15  = lane & 15, quad = lane >> 4;

    // staging constants: row rs = w*16 + lane/4 (0..127), source granule pre-swizzled
    const int rs = (w << 4) + (lane >> 2);
    const int gs = (((lane & 3) ^ ((rs >> 1) & 3)) << 3);
    const size_t soA0 = (size_t)(m0 + rs) * segK + gs;
    const size_t soA1 = soA0 + (size_t)128 * segK;
    const size_t soB0 = (size_t)(n0 + rs) * segK + gs;
    const size_t soB1 = soB0 + (size_t)128 * segK;

    const int ntSeg = segK >> 5;
    const int NT = NSEG * ntSeg;

    auto stA = [&](int kt, int bsel) {
        const ushort_t* S = (NSEG == 2 && kt >= ntSeg) ? A1 : A0;
        int ktl = (NSEG == 2 && kt >= ntSeg) ? kt - ntSeg : kt;
        const ushort_t* s0 = S + ((size_t)ktl << 5);
        ushort_t* d = lds + bsel * 16384 + (w << 9);       // wave-uniform LDS dest
        gload_lds16(s0 + soA0, d);
        gload_lds16(s0 + soA1, d + 4096);
    };
    auto stB = [&](int kt, int bsel) {
        const ushort_t* S = (NSEG == 2 && kt >= ntSeg) ? B1 : B0;
        int ktl = (NSEG == 2 && kt >= ntSeg) ? kt - ntSeg : kt;
        const ushort_t* s0 = S + ((size_t)ktl << 5);
        ushort_t* d = lds + bsel * 16384 + 8192 + (w << 9);
        gload_lds16(s0 + soB0, d);
        gload_lds16(s0 + soB1, d + 4096);
    };

    // ds_read fragment offsets (elements), swizzled to match staging
    int aoffs[8], boffs[4];
#pragma unroll
    for (int mi = 0; mi < 8; ++mi) {
        int r = wm * 128 + mi * 16 + l15;
        aoffs[mi] = (r << 5) + ((quad ^ ((r >> 1) & 3)) << 3);
    }
#pragma unroll
    for (int ni = 0; ni < 4; ++ni) {
        int r = wn * 64 + ni * 16 + l15;
        boffs[ni] = (r << 5) + ((quad ^ ((r >> 1) & 3)) << 3);
    }

    f32x4 acc[8][4] = {};

    // prologue: K-tiles 0 -> buf0, 1 -> buf1; wait tile 0 landed (tile 1 in flight)
    stA(0, 0); stB(0, 0);
    stA(1, 1); stB(1, 1);
    asm volatile("s_waitcnt vmcnt(4)" ::: "memory");
    __builtin_amdgcn_s_barrier();

    int cur = 0, nx2 = 2;
#pragma unroll 1
    for (int kt = 0; kt < NT; ++kt) {
        const ushort_t* LA = lds + cur * 16384;
        const ushort_t* LB = LA + 8192;
        const bool st = (kt + 2 < NT);

        // ---- phase 1: read A(mh0)+B, stage next A, compute mh0 quadrant ----
        bf16x8 af[4], bfr[4];
#pragma unroll
        for (int i = 0; i < 4; ++i) af[i]  = *(const bf16x8*)(LA + aoffs[i]);
#pragma unroll
        for (int i = 0; i < 4; ++i) bfr[i] = *(const bf16x8*)(LB + boffs[i]);
        if (st) stA(kt + 2, nx2);
        __builtin_amdgcn_s_barrier();
        __builtin_amdgcn_s_setprio(1);
#pragma unroll
        for (int mi = 0; mi < 4; ++mi)
#pragma unroll
            for (int ni = 0; ni < 4; ++ni)
                acc[mi][ni] = __builtin_amdgcn_mfma_f32_16x16x32_bf16(af[mi], bfr[ni], acc[mi][ni], 0, 0, 0);
        __builtin_amdgcn_s_setprio(0);
        __builtin_amdgcn_s_barrier();

        // ---- phase 2: read A(mh1), stage next B, compute mh1 quadrant ----
        bf16x8 ag[4];
#pragma unroll
        for (int i = 0; i < 4; ++i) ag[i] = *(const bf16x8*)(LA + aoffs[4 + i]);
        if (st) stB(kt + 2, nx2);
        __builtin_amdgcn_s_barrier();
        __builtin_amdgcn_s_setprio(1);
#pragma unroll
        for (int mi = 0; mi < 4; ++mi)
#pragma unroll
            for (int ni = 0; ni < 4; ++ni)
                acc[4 + mi][ni] = __builtin_amdgcn_mfma_f32_16x16x32_bf16(ag[mi], bfr[ni], acc[4 + mi][ni], 0, 0, 0);
        __builtin_amdgcn_s_setprio(0);

        // group end: pin ordering, counted wait (t+1 landed; t+2 stays in flight)
        __builtin_amdgcn_sched_barrier(0);
        if (st) asm volatile("s_waitcnt vmcnt(4)" ::: "memory");
        else    asm volatile("s_waitcnt vmcnt(0)" ::: "memory");
        __builtin_amdgcn_s_barrier();

        cur = (cur == 2) ? 0 : cur + 1;
        nx2 = (nx2 == 2) ? 0 : nx2 + 1;
    }

#pragma unroll
    for (int mi = 0; mi < 8; ++mi)
#pragma unroll
        for (int ni = 0; ni < 4; ++ni)
            epi(m0 + wm * 128 + mi * 16 + quad * 4, n0 + wn * 64 + ni * 16 + l15, acc[mi][ni]);
}

// ---------------- phase kernels (1 block/CU @ 96KB LDS; chunked XCD swizzle) ----------------
// B: Hm = gelu(Xbf @ W1mT^T + b1m)   M=16384 N=4096 K=1024, tiles 64x16 -> grid 1024
__global__ __launch_bounds__(512, 2) void k_gemm_main1(const ushort_t* __restrict__ Xbf,
                                                       const ushort_t* __restrict__ W1mT,
                                                       const float* __restrict__ b1m,
                                                       ushort_t* __restrict__ Hm) {
    int id = blockIdx.x, xcd = id & 7, s = id >> 3;        // s 0..127
    int tile = xcd * 128 + s;
    int tm = tile >> 4, tn = tile & 15;
    EpiGeluStore epi{Hm, 4096, b1m, 1.0f};
    gemm256<1>(Xbf, Xbf, W1mT, W1mT, 1024, tm * 256, tn * 256, epi);
}
// C: out = a*(Hm @ W2mT^T + b2m)     M=16384 N=1024 K=4096, tiles 64x4 -> grid 256
__global__ __launch_bounds__(512, 2) void k_gemm_main2(const ushort_t* __restrict__ Hm,
                                                       const ushort_t* __restrict__ W2mT,
                                                       const float* __restrict__ b2m,
                                                       const float* __restrict__ alpha,
                                                       float* __restrict__ out) {
    int id = blockIdx.x, xcd = id & 7, s = id >> 3;        // s 0..31
    int tile = xcd * 32 + s;
    int tm = tile >> 2, tn = tile & 3;
    float a = fminf(fmaxf(alpha[0], 0.1f), 1.0f);
    EpiMainOut epi{out, b2m, a};
    gemm256<1>(Hm, Hm, W2mT, W2mT, 4096, tm * 256, tn * 256, epi);
}
// D: He[j] = gsw[j]*gelu(Xbf[b] @ W1eT[e]^T + b1e[e])  32 x (M=1024 N=4096 K=1024), grid 2048
__global__ __launch_bounds__(512, 2) void k_gemm_exp1(const ushort_t* __restrict__ Xbf,
                                                      const ushort_t* __restrict__ W1eT,
                                                      const float* __restrict__ b1e,
                                                      const int* __restrict__ eidx,
                                                      const float* __restrict__ gsw,
                                                      ushort_t* __restrict__ He) {
    int id = blockIdx.x, xcd = id & 7, s = id >> 3;        // s 0..255
    int j = xcd * 4 + (s >> 6);                            // 4 assignments per XCD
    int t = s & 63;
    int tm = t >> 4, tn = t & 15;
    int b = j >> 1;
    int e = eidx[j];
    float gs = gsw[j];
    const ushort_t* A = Xbf + (size_t)b * 1024 * 1024;
    const ushort_t* Bm = W1eT + (size_t)e * 4096 * 1024;
    EpiGeluStore epi{He + (size_t)j * 1024 * 4096, 4096, b1e + (size_t)e * 4096, gs};
    gemm256<1>(A, A, Bm, Bm, 1024, tm * 256, tn * 256, epi);
}
// E: out[b] += sum_k He[b,k] @ W2eT[ek]^T + gs_k*b2e[ek]  16 x (M=1024 N=1024 K=2x4096), grid 256
__global__ __launch_bounds__(512, 2) void k_gemm_exp2(const ushort_t* __restrict__ He,
                                                      const ushort_t* __restrict__ W2eT,
                                                      const float* __restrict__ b2e,
                                                      const int* __restrict__ eidx,
                                                      const float* __restrict__ gsw,
                                                      float* __restrict__ out) {
    int id = blockIdx.x, xcd = id & 7, s = id >> 3;        // s 0..31
    int b = xcd * 2 + (s >> 4);
    int t = s & 15;
    int tm = t >> 2, tn = t & 3;
    int e0 = eidx[2 * b], e1 = eidx[2 * b + 1];
    EpiExpertOut epi{out + (size_t)b * 1024 * 1024,
                     b2e + (size_t)e0 * 1024, b2e + (size_t)e1 * 1024,
                     gsw[2 * b], gsw[2 * b + 1]};
    gemm256<2>(He + (size_t)(2 * b) * 1024 * 4096, He + (size_t)(2 * b + 1) * 1024 * 4096,
               W2eT + (size_t)e0 * 1024 * 4096, W2eT + (size_t)e1 * 1024 * 4096,
               4096, tm * 256, tn * 256, epi);
}

extern "C" void kernel_launch(void* const* d_in, const int* in_sizes, int n_in,
                              void* d_out, int out_size, void* d_ws, size_t ws_size,
                              hipStream_t stream) {
    const float* x      = (const float*)d_in[0];
    const float* alpha  = (const float*)d_in[1];
    const float* w_gate = (const float*)d_in[2];
    const float* b_gate = (const float*)d_in[3];
    const float* W1m    = (const float*)d_in[4];
    const float* b1m    = (const float*)d_in[5];
    const float* W2m    = (const float*)d_in[6];
    const float* b2m    = (const float*)d_in[7];
    const float* W1e    = (const float*)d_in[8];
    const float* b1e    = (const float*)d_in[9];
    const float* W2e    = (const float*)d_in[10];
    const float* b2e    = (const float*)d_in[11];
    float* out = (float*)d_out;

    char* ws = (char*)d_ws;
    size_t off = 0;
    ushort_t* Xbf  = (ushort_t*)(ws + off); off += (size_t)16384 * 1024 * 2;
    ushort_t* W1mT = (ushort_t*)(ws + off); off += (size_t)4096 * 1024 * 2;
    ushort_t* W2mT = (ushort_t*)(ws + off); off += (size_t)4096 * 1024 * 2;
    ushort_t* W1eT = (ushort_t*)(ws + off); off += (size_t)8 * 4096 * 1024 * 2;
    ushort_t* W2eT = (ushort_t*)(ws + off); off += (size_t)8 * 4096 * 1024 * 2;
    float*    part = (float*)(ws + off);    off += (size_t)16 * 16 * 1024 * 4;
    int*      eidx = (int*)(ws + off);      off += 256;
    float*    gsw  = (float*)(ws + off);    off += 256;
    ushort_t* He   = (ushort_t*)(ws + off);
    ushort_t* Hm   = He;  // alias: Hm dead (after main2) before He written (exp1)
    off += (size_t)32 * 1024 * 4096 * 2;
    if (ws_size < off) return;

    k_convert_x_pool<<<dim3(16, 16), 256, 0, stream>>>(x, Xbf, part);
    k_router<<<16, 256, 0, stream>>>(part, w_gate, b_gate, alpha, eidx, gsw);
    k_transpose_cvt<<<dim3(64, 16, 1), 256, 0, stream>>>(W1m, W1mT, 1024, 4096);
    k_transpose_cvt<<<dim3(16, 64, 1), 256, 0, stream>>>(W2m, W2mT, 4096, 1024);
    k_transpose_cvt<<<dim3(64, 16, 8), 256, 0, stream>>>(W1e, W1eT, 1024, 4096);
    k_transpose_cvt<<<dim3(16, 64, 8), 256, 0, stream>>>(W2e, W2eT, 4096, 1024);
    k_gemm_main1<<<1024, 512, 0, stream>>>(Xbf, W1mT, b1m, Hm);
    k_gemm_main2<<<256, 512, 0, stream>>>(Hm, W2mT, b2m, alpha, out);
    k_gemm_exp1<<<2048, 512, 0, stream>>>(Xbf, W1eT, b1e, eidx, gsw, He);
    k_gemm_exp2<<<256, 512, 0, stream>>>(He, W2eT, b2e, eidx, gsw, out);
}